// Round 3
// baseline (806.187 us; speedup 1.0000x reference)
//
#include <hip/hip_runtime.h>

#define BS 256
#define NFEAT 121
#define SST 21   // per-thread LDS staging row (floats) = widest phase (f10).
                 // 21 odd -> t*21 mod 32 permutes banks -> 2-way alias (free).

// Feature f_l occupies output cols [l*l, l*l+2l+1). Phases (width <= 21):
//   P1 f0..f3 cols [0,16)   P2 f4,f5 cols [16,36)  P3 f6 [36,49)  P4 f7 [49,64)
//   P5 f8 [64,81)  P6 f9 [81,100)  P7 f10 [100,121)
// Each wave stages into its OWN 64-row LDS slab and flushes it itself ->
// zero __syncthreads (lockstep wave + in-order LDS pipe; aliasing between the
// staging writes and flush reads is VISIBLE to the compiler -- no __restrict__
// on LDS pointers -- so it inserts the lgkmcnt waits).

__device__ __forceinline__ float dot3(const float* __restrict__ c, float x, float y, float z) {
    return fmaf(c[2], z, fmaf(c[1], y, c[0] * x));
}

// One order step: srow[colofs+j] = sum_a prev[a] * dot3(cob[j,3a..], f1)
// j-loop rolled (small I-cache, cob row via s_load); a-loop unrolled (prev in regs).
template<int LL, bool UPDATE_PREV>
__device__ __forceinline__ void step_l(const float* __restrict__ cob,
                                       float* srow, int colofs,
                                       float f1x, float f1y, float f1z,
                                       float* prev) {
    constexpr int IN  = 2 * LL - 1;
    constexpr int OUT = 2 * LL + 1;
    #pragma unroll 1
    for (int j = 0; j < OUT; ++j) {
        const float* __restrict__ crow = cob + j * (3 * IN);  // wave-uniform -> s_load
        float acc = 0.f;
        #pragma unroll
        for (int a = 0; a < IN; ++a) {
            float s = dot3(crow + 3 * a, f1x, f1y, f1z);
            acc = fmaf(prev[a], s, acc);
        }
        srow[colofs + j] = acc;
    }
    if (UPDATE_PREV) {
        #pragma unroll
        for (int j = 0; j < OUT; ++j) prev[j] = srow[colofs + j];
    }
}

// Per-wave coalesced flush: W staged columns for this wave's 64 rows.
// Lane -> (lr = lane/W, lc = lane%W) computed ONCE; each iteration advances
// RPI = 64/W rows, so addresses advance by compile-time constants (no per-elem
// div, no per-elem 64-bit math). Store pattern = runs of W consecutive floats.
template<int W>
__device__ __forceinline__ void wave_flush(const float* slab,
                                           float* __restrict__ outw,
                                           int wrows, int lane) {
    constexpr int RPI   = 64 / W;               // rows per iteration
    constexpr int LANES = RPI * W;              // active lanes
    constexpr int ITERS = (64 + RPI - 1) / RPI;
    const int lr = lane / W;                    // constexpr divisor -> magic mul, once
    const int lc = lane - lr * W;
    if (lane < LANES) {
        const float* sp = slab + lr * SST + lc;
        float* __restrict__ gp = outw + lr * NFEAT + lc;
        if (wrows == 64) {                      // wave-uniform branch (bulk case)
            #pragma unroll
            for (int k = 0; k < ITERS; ++k) {
                const bool safe = (k * RPI + RPI - 1) < 64;   // folds per unrolled k
                if (safe || (k * RPI + lr) < 64)
                    gp[k * RPI * NFEAT] = sp[k * RPI * SST];
            }
        } else {                                // tail block only
            #pragma unroll
            for (int k = 0; k < ITERS; ++k) {
                if (k * RPI + lr < wrows)
                    gp[k * RPI * NFEAT] = sp[k * RPI * SST];
            }
        }
    }
}

__global__ __launch_bounds__(BS) void harmonic_kernel(
    const float* __restrict__ points,
    const float* __restrict__ cob1,  const float* __restrict__ cob2,
    const float* __restrict__ cob3,  const float* __restrict__ cob4,
    const float* __restrict__ cob5,  const float* __restrict__ cob6,
    const float* __restrict__ cob7,  const float* __restrict__ cob8,
    const float* __restrict__ cob9,  const float* __restrict__ cob10,
    float* __restrict__ out, int N) {
    __shared__ float sbuf[BS * SST];   // 21,504 B -> up to 7 blocks/CU by LDS

    const int t    = threadIdx.x;
    const int lane = t & 63;
    const int w    = t >> 6;
    const long long p0    = (long long)blockIdx.x * BS;
    const long long wbase = p0 + (w << 6);
    const long long p     = wbase + lane;
    const bool active = p < (long long)N;

    long long nv = (long long)N - wbase;
    const int wrows = nv >= 64 ? 64 : (nv > 0 ? (int)nv : 0);

    float px = 0.f, py = 0.f, pz = 0.f;
    if (active) {
        px = points[p * 3 + 0];
        py = points[p * 3 + 1];
        pz = points[p * 3 + 2];
    }

    // f1[j] = sum_i points[i] * cob1[j,i]
    const float f1x = dot3(cob1 + 0, px, py, pz);
    const float f1y = dot3(cob1 + 3, px, py, pz);
    const float f1z = dot3(cob1 + 6, px, py, pz);

    float prev[21];
    prev[0] = f1x; prev[1] = f1y; prev[2] = f1z;

    float* srow       = sbuf + t * SST;          // this thread's staging row
    const float* slab = sbuf + (w << 6) * SST;   // this wave's 64 rows (aliases srow!)
    float* __restrict__ outw = out + wbase * NFEAT;

    // ---- P1: f0..f3 -> cols [0,16) ----
    srow[0] = 1.f;
    srow[1] = f1x; srow[2] = f1y; srow[3] = f1z;
    step_l<2, true>(cob2, srow, 4, f1x, f1y, f1z, prev);
    step_l<3, true>(cob3, srow, 9, f1x, f1y, f1z, prev);
    wave_flush<16>(slab, outw + 0, wrows, lane);

    // ---- P2: f4,f5 -> cols [16,36) ----
    step_l<4, true>(cob4, srow, 0, f1x, f1y, f1z, prev);
    step_l<5, true>(cob5, srow, 9, f1x, f1y, f1z, prev);
    wave_flush<20>(slab, outw + 16, wrows, lane);

    // ---- P3: f6 -> cols [36,49) ----
    step_l<6, true>(cob6, srow, 0, f1x, f1y, f1z, prev);
    wave_flush<13>(slab, outw + 36, wrows, lane);

    // ---- P4: f7 -> cols [49,64) ----
    step_l<7, true>(cob7, srow, 0, f1x, f1y, f1z, prev);
    wave_flush<15>(slab, outw + 49, wrows, lane);

    // ---- P5: f8 -> cols [64,81) ----
    step_l<8, true>(cob8, srow, 0, f1x, f1y, f1z, prev);
    wave_flush<17>(slab, outw + 64, wrows, lane);

    // ---- P6: f9 -> cols [81,100) ----
    step_l<9, true>(cob9, srow, 0, f1x, f1y, f1z, prev);
    wave_flush<19>(slab, outw + 81, wrows, lane);

    // ---- P7: f10 -> cols [100,121) ----
    step_l<10, false>(cob10, srow, 0, f1x, f1y, f1z, prev);
    wave_flush<21>(slab, outw + 100, wrows, lane);
}

extern "C" void kernel_launch(void* const* d_in, const int* in_sizes, int n_in,
                              void* d_out, int out_size, void* d_ws, size_t ws_size,
                              hipStream_t stream) {
    const float* points = (const float*)d_in[0];
    const float* cob[10];
    for (int i = 0; i < 10; ++i) cob[i] = (const float*)d_in[1 + i];
    float* out = (float*)d_out;
    const int N = in_sizes[0] / 3;

    const int grid = (N + BS - 1) / BS;
    harmonic_kernel<<<grid, BS, 0, stream>>>(
        points,
        cob[0], cob[1], cob[2], cob[3], cob[4],
        cob[5], cob[6], cob[7], cob[8], cob[9],
        out, N);
}

// Round 4
// 726.124 us; speedup vs baseline: 1.1103x; 1.1103x over previous
//
#include <hip/hip_runtime.h>

#define BS 64        // one wave per block; N=1e6 = 15625 * 64 exactly (tail path kept anyway)
#define NFEAT 121
#define CHUNK 16     // rows per flush chunk
#define NCHUNK 4     // BS / CHUNK

// All 121 features live in REGISTERS (fully static indexing). Single flush at the
// end streams each wave's 64x121 slab (= exactly 484 full 64B lines) contiguously:
// no column-phase partial-line boundaries -> write amplification ~1.0x (was 1.48x).

__device__ __forceinline__ float dot3(const float* __restrict__ c, float x, float y, float z) {
    return fmaf(c[2], z, fmaf(c[1], y, c[0] * x));
}

// f[l*l + j] = sum_a f[(l-1)^2 + a] * dot3(cob_l[j, 3a..], f1)   -- fully unrolled,
// all f[] indices compile-time -> stays in VGPRs (no scratch, no LDS round-trip).
template<int LL>
__device__ __forceinline__ void step_l(const float* __restrict__ cob,
                                       float* f, float f1x, float f1y, float f1z) {
    constexpr int IN = 2 * LL - 1;
    constexpr int OUT = 2 * LL + 1;
    constexpr int PB = (LL - 1) * (LL - 1);
    constexpr int OB = LL * LL;
    #pragma unroll
    for (int j = 0; j < OUT; ++j) {
        const float* __restrict__ crow = cob + j * (3 * IN);  // wave-uniform -> s_load
        float acc = 0.f;
        #pragma unroll
        for (int a = 0; a < IN; ++a)
            acc = fmaf(f[PB + a], dot3(crow + 3 * a, f1x, f1y, f1z), acc);
        f[OB + j] = acc;
    }
}

__global__ __launch_bounds__(BS) void harmonic_kernel(
    const float* __restrict__ points,
    const float* __restrict__ cob1,  const float* __restrict__ cob2,
    const float* __restrict__ cob3,  const float* __restrict__ cob4,
    const float* __restrict__ cob5,  const float* __restrict__ cob6,
    const float* __restrict__ cob7,  const float* __restrict__ cob8,
    const float* __restrict__ cob9,  const float* __restrict__ cob10,
    float* __restrict__ out, int N) {
    __shared__ float sbuf[CHUNK * NFEAT];   // 7744 B; one wave per block -> private

    const int lane = threadIdx.x;
    const long long wbase = (long long)blockIdx.x * BS;
    const long long p = wbase + lane;
    const bool active = p < (long long)N;
    long long nv = (long long)N - wbase;
    const int wrows = nv >= BS ? BS : (nv > 0 ? (int)nv : 0);

    float px = 0.f, py = 0.f, pz = 0.f;
    if (active) {
        px = points[p * 3 + 0];
        py = points[p * 3 + 1];
        pz = points[p * 3 + 2];
    }

    const float f1x = dot3(cob1 + 0, px, py, pz);
    const float f1y = dot3(cob1 + 3, px, py, pz);
    const float f1z = dot3(cob1 + 6, px, py, pz);

    float f[NFEAT];
    f[0] = 1.f; f[1] = f1x; f[2] = f1y; f[3] = f1z;
    step_l<2>(cob2, f, f1x, f1y, f1z);
    step_l<3>(cob3, f, f1x, f1y, f1z);
    step_l<4>(cob4, f, f1x, f1y, f1z);
    step_l<5>(cob5, f, f1x, f1y, f1z);
    step_l<6>(cob6, f, f1x, f1y, f1z);
    step_l<7>(cob7, f, f1x, f1y, f1z);
    step_l<8>(cob8, f, f1x, f1y, f1z);
    step_l<9>(cob9, f, f1x, f1y, f1z);
    step_l<10>(cob10, f, f1x, f1y, f1z);

    // ---- Single flush: 4 chunks of 16 rows through LDS, streamed contiguously ----
    // ds_write: 16 active lanes, LDS word stride 121 (odd) -> 16 distinct banks, conflict-free.
    // ds_read/store: consecutive lanes, consecutive words -> 2 lanes/bank (free), stores are
    // 256 B contiguous per instruction, sequential over the whole 30,976 B slab.
    // Same-wave LDS ops execute in order (aliasing via sbuf visible to compiler -> lgkmcnt waits),
    // so chunk c+1's writes can't pass chunk c's reads. No barriers needed.
    float* __restrict__ outw = out + wbase * NFEAT;
    const int myc = lane >> 4;       // this lane's chunk
    const int mr  = lane & 15;       // row within chunk

    if (wrows == BS) {               // bulk path (wave-uniform)
        #pragma unroll 1
        for (int c = 0; c < NCHUNK; ++c) {
            if (myc == c) {
                #pragma unroll
                for (int col = 0; col < NFEAT; ++col)
                    sbuf[mr * NFEAT + col] = f[col];
            }
            const int gbase = c * (CHUNK * NFEAT);   // 1936 floats per chunk
            #pragma unroll
            for (int k = 0; k < 30; ++k)             // 30*64 = 1920
                outw[gbase + k * 64 + lane] = sbuf[k * 64 + lane];
            if (lane < 16)                           // tail 16 floats
                outw[gbase + 1920 + lane] = sbuf[1920 + lane];
        }
    } else if (wrows > 0) {          // tail block (generality; unused for N=1e6)
        #pragma unroll 1
        for (int c = 0; c < NCHUNK; ++c) {
            int vr = wrows - c * CHUNK;
            if (vr <= 0) break;
            if (vr > CHUNK) vr = CHUNK;
            if (myc == c && mr < vr) {
                #pragma unroll
                for (int col = 0; col < NFEAT; ++col)
                    sbuf[mr * NFEAT + col] = f[col];
            }
            const int gbase = c * (CHUNK * NFEAT);
            const int nf = vr * NFEAT;
            #pragma unroll 1
            for (int k = 0; k < 31; ++k) {
                const int idx = k * 64 + lane;
                if (idx < nf) outw[gbase + idx] = sbuf[idx];
            }
        }
    }
}

extern "C" void kernel_launch(void* const* d_in, const int* in_sizes, int n_in,
                              void* d_out, int out_size, void* d_ws, size_t ws_size,
                              hipStream_t stream) {
    const float* points = (const float*)d_in[0];
    const float* cob[10];
    for (int i = 0; i < 10; ++i) cob[i] = (const float*)d_in[1 + i];
    float* out = (float*)d_out;
    const int N = in_sizes[0] / 3;

    const int grid = (N + BS - 1) / BS;
    harmonic_kernel<<<grid, BS, 0, stream>>>(
        points,
        cob[0], cob[1], cob[2], cob[3], cob[4],
        cob[5], cob[6], cob[7], cob[8], cob[9],
        out, N);
}